// Round 15
// baseline (942.660 us; speedup 1.0000x reference)
//
#include <hip/hip_runtime.h>
#include <math.h>

#define BB 32
#define HH 1024
#define TT 100
#define TH (TT * HH)
#define NSTEP 200
#define TILE 32768           // halves per packed [chunk 128][row 32][8] activation tile
#define SENT 0x7F7Fu         // fp16 NaN pattern used as "not yet written" sentinel

typedef _Float16 half8 __attribute__((ext_vector_type(8)));
typedef float f32x4 __attribute__((ext_vector_type(4)));
typedef unsigned int uint4v __attribute__((ext_vector_type(4)));

#define MFMA16 __builtin_amdgcn_mfma_f32_16x16x32_f16

// ---------------- coherence-point (LLC) access helpers ----------------
__device__ __forceinline__ void llc_ld_nw(const _Float16* p, half8& v) {
    asm volatile("global_load_dwordx4 %0, %1, off sc0 sc1" : "=v"(v) : "v"(p) : "memory");
}
__device__ __forceinline__ bool frag_ready(half8 v) {
    uint4v u = __builtin_bit_cast(uint4v, v);
    // one marker per 8-byte atomic unit (elements 0 and 4)
    return ((u.x & 0xFFFFu) != SENT) & ((u.z & 0xFFFFu) != SENT);
}

// issue all 16 fragment loads of this wave's k-slice into buf (no wait)
#define ISSUE_FRAGS(buf)                                              \
    do {                                                              \
        llc_ld_nw(aptr,       buf[0]);                                \
        llc_ld_nw(aptr + 128, buf[1]);                                \
        _Pragma("unroll")                                             \
        for (int s_ = 1; s_ < 8; ++s_) {                              \
            llc_ld_nw(aptr + s_ * 1024,       buf[2 * s_]);           \
            llc_ld_nw(aptr + s_ * 1024 + 128, buf[2 * s_ + 1]);       \
        }                                                             \
    } while (0)

// wait until only the most recent 16 loads remain outstanding; ties buf regs
#define WAIT_OTHER16(buf)                                             \
    do {                                                              \
        asm volatile("s_waitcnt vmcnt(16)"                            \
            : "+v"(buf[0]),  "+v"(buf[1]),  "+v"(buf[2]),  "+v"(buf[3]),   \
              "+v"(buf[4]),  "+v"(buf[5]),  "+v"(buf[6]),  "+v"(buf[7]),   \
              "+v"(buf[8]),  "+v"(buf[9]),  "+v"(buf[10]), "+v"(buf[11]),  \
              "+v"(buf[12]), "+v"(buf[13]), "+v"(buf[14]), "+v"(buf[15])   \
            :: "memory");                                             \
        __builtin_amdgcn_sched_barrier(0);                            \
    } while (0)

// formally read all 16 regs of buf — keeps them allocated (placed AFTER the
// vmcnt(0) drain so no outstanding load can clobber a reused register)
#define KEEPALIVE(buf)                                                \
    asm volatile(""                                                   \
        :: "v"(buf[0]),  "v"(buf[1]),  "v"(buf[2]),  "v"(buf[3]),     \
           "v"(buf[4]),  "v"(buf[5]),  "v"(buf[6]),  "v"(buf[7]),     \
           "v"(buf[8]),  "v"(buf[9]),  "v"(buf[10]), "v"(buf[11]),    \
           "v"(buf[12]), "v"(buf[13]), "v"(buf[14]), "v"(buf[15]))

#define RUN_MFMA(buf)                                                      \
    do {                                                                   \
        _Pragma("unroll")                                                  \
        for (int s_ = 0; s_ < 8; ++s_) {                                   \
            acc[0][0] = MFMA16(buf[2 * s_],     wreg[2 * s_],     acc[0][0], 0, 0, 0); \
            acc[0][1] = MFMA16(buf[2 * s_],     wreg[2 * s_ + 1], acc[0][1], 0, 0, 0); \
            acc[1][0] = MFMA16(buf[2 * s_ + 1], wreg[2 * s_],     acc[1][0], 0, 0, 0); \
            acc[1][1] = MFMA16(buf[2 * s_ + 1], wreg[2 * s_ + 1], acc[1][1], 0, 0, 0); \
        }                                                                  \
    } while (0)

// ---------------- bias sum ----------------
__global__ __launch_bounds__(256) void bias_sum_kernel(
    const float* bih0, const float* bhh0, const float* bih1, const float* bhh1,
    float* bsum0, float* bsum1)
{
    int i = blockIdx.x * blockDim.x + threadIdx.x;
    if (i < 4096)      bsum0[i] = bih0[i] + bhh0[i];
    else if (i < 8192) bsum1[i - 4096] = bih1[i - 4096] + bhh1[i - 4096];
}

// ------- x / targets -> fp16, packed fragment layout [t][chunk][row][8] ------
__global__ __launch_bounds__(256) void cvt_pack_x(
    const float* __restrict__ X, const float* __restrict__ Tg,
    _Float16* __restrict__ X16, _Float16* __restrict__ Tg16)
{
    int id  = blockIdx.x * 256 + threadIdx.x;   // 0 .. 819199
    int tsr = id / 409600;
    int rem = id - tsr * 409600;
    int t   = rem >> 12;          // 0..99
    int rb  = rem & 4095;
    int h8  = rb >> 5;            // chunk 0..127
    int b   = rb & 31;            // row
    const float* s = tsr ? Tg : X;
    _Float16*    d = tsr ? Tg16 : X16;
    const float* sp = s + (size_t)b * TH + (size_t)t * HH + h8 * 8;
    float4 v0 = *(const float4*)sp;
    float4 v1 = *(const float4*)(sp + 4);
    half8 h;
    h[0] = (_Float16)v0.x; h[1] = (_Float16)v0.y; h[2] = (_Float16)v0.z; h[3] = (_Float16)v0.w;
    h[4] = (_Float16)v1.x; h[5] = (_Float16)v1.y; h[6] = (_Float16)v1.z; h[7] = (_Float16)v1.w;
    *(half8*)(d + (size_t)t * TILE + ((size_t)h8 * 32 + b) * 8) = h;
}

// ---------------- weight packing (fp16, MFMA B-fragment stream order) --------
__global__ __launch_bounds__(256) void pack_w(
    const float* __restrict__ Wih0, const float* __restrict__ Whh0,
    const float* __restrict__ Wih1, const float* __restrict__ Whh1,
    _Float16* __restrict__ Wp0, _Float16* __restrict__ Wp1)
{
    int id    = blockIdx.x * 256 + threadIdx.x;   // 0 .. 2^21-1
    int lane  = id & 63;
    int nt    = (id >> 6) & 1;
    int s     = (id >> 7) & 7;
    int w     = (id >> 10) & 7;
    int hb    = (id >> 13) & 127;
    int layer = id >> 20;
    const float* Wih = layer ? Wih1 : Wih0;
    const float* Whh = layer ? Whh1 : Whh0;
    _Float16*    Wp  = layer ? Wp1 : Wp0;

    int nl   = nt * 16 + (lane & 15);
    int gate = nl >> 3;
    int col  = hb * 8 + (nl & 7);
    int n    = gate * HH + col;
    int k    = w * 256 + s * 32 + ((lane >> 4) & 3) * 8;
    const float* src = (k < 1024) ? (Wih + (size_t)n * HH + k)
                                  : (Whh + (size_t)n * HH + (k - 1024));
    float4 v0 = *(const float4*)src;
    float4 v1 = *(const float4*)(src + 4);
    half8 d;
    d[0] = (_Float16)v0.x; d[1] = (_Float16)v0.y; d[2] = (_Float16)v0.z; d[3] = (_Float16)v0.w;
    d[4] = (_Float16)v1.x; d[5] = (_Float16)v1.y; d[6] = (_Float16)v1.z; d[7] = (_Float16)v1.w;
    *(half8*)(Wp + (size_t)(id & 0xFFFFF) * 8) = d;
}

// ---------------- persistent pipelined LSTM (pure dataflow sync) -------------
struct PArgs {
    const _Float16* X16;    // [T][TILE] packed
    const _Float16* Tg16;   // [T][TILE] packed
    const _Float16* Wp0;
    const _Float16* Wp1;
    const float* bsum0;
    const float* bsum1;
    _Float16* h0r;          // [201][TILE]; slot t+1 = h[t]; slot 0 = zeros;
    _Float16* h1r;          //   unwritten slots pre-filled with SENT pattern
    float* out;             // [B][T][H]
};

__global__ __launch_bounds__(512, 2) void lstm_persist(PArgs A)
{
    __shared__ float part[8][32][34];     // 34.8 KB
    __shared__ float ldspad[11776];       // total 80 KB -> 1 WG/CU

    const int wg   = blockIdx.x;
    const int role = wg >> 7;
    const int hb   = wg & 127;
    const int tid  = threadIdx.x;
    const int w    = tid >> 6;
    const int lane = tid & 63;
    const int lr   = lane & 15;
    const int lg   = lane >> 4;
    const bool isx = (w < 4);

    if (A.out == (float*)1) {             // never true; keeps ldspad allocated
        ldspad[tid] = (float)tid;
        part[0][0][0] = ldspad[511 - tid];
    }

    const _Float16* Wp   = role ? A.Wp1 : A.Wp0;
    const float* bsum    = role ? A.bsum1 : A.bsum0;
    _Float16* ring_self  = role ? A.h1r : A.h0r;

    // ---- one-time: weight slice -> registers ----
    half8 wreg[16];
    {
        const half8* wp = (const half8*)Wp + (size_t)(hb * 8 + w) * 1024 + lane;
#pragma unroll
        for (int sn = 0; sn < 16; ++sn) wreg[sn] = wp[(size_t)sn * 64];
    }

    const int eb = tid >> 3, ec = tid & 7, ecol = hb * 8 + ec;
    float breg[4], creg = 0.f;
    if (tid < 256) {
#pragma unroll
        for (int g = 0; g < 4; ++g) breg[g] = bsum[g * HH + ecol];
    }

    // per-lane A-fragment offset within a packed tile (halves)
    const size_t afrag = (size_t)((w & 3) * 32 + lg) * 256 + (size_t)lr * 8;
    bool dead = false;

    for (int p = 0; p < NSTEP; ++p) {
        half8 va[16], vb[16];
        int use = 0;
        const bool early = isx && role == 0 && p != 100;
        if (early) {
            // static input: plain cached loads into va
            const _Float16* aptr = ((p < 100) ? A.X16 + (size_t)p * TILE
                                              : A.Tg16 + (size_t)(p - 100) * TILE) + afrag;
#pragma unroll
            for (int s = 0; s < 8; ++s) {
                va[2 * s]     = *(const half8*)(aptr + s * 1024);
                va[2 * s + 1] = *(const half8*)(aptr + s * 1024 + 128);
            }
        } else {
            // ring tile: double-buffered fused poll+fetch. Alternating register
            // copies keep 16 fragments always in flight -> check cadence ~RT/2.
            // The winning buffer feeds MFMA directly (no copy); the loser's
            // in-flight loads are drained + kept alive before reg reuse.
            const _Float16* abase;
            if (isx) abase = role ? A.h0r + (size_t)(p + 1) * TILE
                                  : A.h1r + (size_t)100 * TILE;   // p==100
            else     abase = ring_self + (size_t)p * TILE;
            const _Float16* aptr = abase + afrag;

            unsigned spins = 0;
            // drain prior ops so counted vmcnt is exact
            asm volatile("s_waitcnt vmcnt(0)" ::: "memory");
            if (!dead) {
                ISSUE_FRAGS(va);                      // 16 outstanding
                for (;;) {
                    ISSUE_FRAGS(vb);                  // 32 outstanding
                    WAIT_OTHER16(va);                 // va arrived; vb in flight
                    bool ok = true;
#pragma unroll
                    for (int i = 0; i < 16; ++i) ok &= frag_ready(va[i]);
                    if (__all(ok)) { use = 0; break; }
                    if (++spins > (1u << 20)) { dead = true; use = 0; break; }

                    ISSUE_FRAGS(va);                  // 32 outstanding
                    WAIT_OTHER16(vb);                 // vb arrived; va in flight
                    ok = true;
#pragma unroll
                    for (int i = 0; i < 16; ++i) ok &= frag_ready(vb[i]);
                    if (__all(ok)) { use = 1; break; }
                    if (++spins > (1u << 20)) { dead = true; use = 1; break; }
                }
            }
        }

        // ---------- MFMA: 32 per wave, weights from registers ----------
        f32x4 acc[2][2] = {};
        if (use == 0) RUN_MFMA(va);
        else          RUN_MFMA(vb);

        // ---------- cross-wave reduction ----------
#pragma unroll
        for (int mt = 0; mt < 2; ++mt)
#pragma unroll
            for (int nt = 0; nt < 2; ++nt)
#pragma unroll
                for (int j = 0; j < 4; ++j)
                    part[w][16 * mt + lg * 4 + j][16 * nt + lr] = acc[mt][nt][j];

        if (!early) {
            // drain the loser buffer's in-flight loads (overlapped with the
            // MFMA/LDS work above), then formally read BOTH buffers so the
            // compiler cannot reuse their registers before the drain point.
            asm volatile("s_waitcnt vmcnt(0)" ::: "memory");
            KEEPALIVE(va);
            KEEPALIVE(vb);
        }
        __syncthreads();

        // ---------- fused cell epilogue ----------
        if (tid < 256) {
            float g4[4];
#pragma unroll
            for (int g = 0; g < 4; ++g) {
                float s0 = 0.f;
#pragma unroll
                for (int pw = 0; pw < 8; ++pw) s0 += part[pw][eb][g * 8 + ec];
                g4[g] = s0 + breg[g];
            }
            float ig = 1.f / (1.f + __expf(-g4[0]));
            float fg = 1.f / (1.f + __expf(-g4[1]));
            float gg = 2.f / (1.f + __expf(-2.f * g4[2])) - 1.f;
            float og = 1.f / (1.f + __expf(-g4[3]));
            float cn = fg * creg + ig * gg;
            float tc = 2.f / (1.f + __expf(-2.f * cn)) - 1.f;
            float hn = og * tc;
            creg = cn;

            // pack 4 adjacent u16 h values -> one 8B agent-scope atomic swap
            unsigned hv = (unsigned)__builtin_bit_cast(unsigned short, (_Float16)hn);
            unsigned o1  = __shfl_xor(hv, 1, 64);
            unsigned w32 = hv | (o1 << 16);                 // valid on even tid
            unsigned o2  = __shfl_xor(w32, 2, 64);
            if ((tid & 3) == 0) {
                unsigned long long d64 =
                    ((unsigned long long)o2 << 32) | (unsigned long long)w32;
                unsigned long long* dst = (unsigned long long*)
                    (ring_self + (size_t)(p + 1) * TILE + hb * 256 + tid);
                __hip_atomic_exchange(dst, d64, __ATOMIC_RELAXED,
                                      __HIP_MEMORY_SCOPE_AGENT);
            }
            if (role && p >= 100)
                A.out[(size_t)eb * TH + (size_t)(p - 100) * HH + ecol] = hn;
        }
        __syncthreads();   // protects part[] across steps; atomics already issued
    }
}

extern "C" void kernel_launch(void* const* d_in, const int* in_sizes, int n_in,
                              void* d_out, int out_size, void* d_ws, size_t ws_size,
                              hipStream_t stream)
{
    const float* X    = (const float*)d_in[0];
    const float* Tg   = (const float*)d_in[1];
    const float* Wih0 = (const float*)d_in[2];
    const float* Whh0 = (const float*)d_in[3];
    const float* bih0 = (const float*)d_in[4];
    const float* bhh0 = (const float*)d_in[5];
    const float* Wih1 = (const float*)d_in[6];
    const float* Whh1 = (const float*)d_in[7];
    const float* bih1 = (const float*)d_in[8];
    const float* bhh1 = (const float*)d_in[9];
    float* out = (float*)d_out;

    const size_t ringBytes = (size_t)201 * TILE * 2;   // 13.2 MB
    char* p = (char*)d_ws;
    _Float16* h0r = (_Float16*)p; p += ringBytes;
    _Float16* h1r = (_Float16*)p; p += ringBytes;
    float* bsum0 = (float*)p; p += 4096 * sizeof(float);
    float* bsum1 = (float*)p; p += 4096 * sizeof(float);
    _Float16* X16  = (_Float16*)p; p += (size_t)TT * TILE * 2;
    _Float16* Tg16 = (_Float16*)p; p += (size_t)TT * TILE * 2;
    _Float16* Wp0  = (_Float16*)p; p += (size_t)4096 * 2048 * 2;
    _Float16* Wp1  = (_Float16*)p;

    // sentinel-fill rings (0x7F7F halves = fp16 NaN, unreachable by tanh*sig),
    // then zero slot 0 of each ring (h[-1] = 0)
    hipMemsetAsync(h0r, 0x7F, ringBytes, stream);
    hipMemsetAsync(h1r, 0x7F, ringBytes, stream);
    hipMemsetAsync(h0r, 0, (size_t)TILE * 2, stream);
    hipMemsetAsync(h1r, 0, (size_t)TILE * 2, stream);

    bias_sum_kernel<<<32, 256, 0, stream>>>(bih0, bhh0, bih1, bhh1, bsum0, bsum1);
    cvt_pack_x<<<3200, 256, 0, stream>>>(X, Tg, X16, Tg16);
    pack_w<<<8192, 256, 0, stream>>>(Wih0, Whh0, Wih1, Whh1, Wp0, Wp1);

    PArgs A;
    A.X16 = X16; A.Tg16 = Tg16; A.Wp0 = Wp0; A.Wp1 = Wp1;
    A.bsum0 = bsum0; A.bsum1 = bsum1;
    A.h0r = h0r; A.h1r = h1r;
    A.out = out;
    lstm_persist<<<256, 512, 0, stream>>>(A);
}

// Round 16
// 873.715 us; speedup vs baseline: 1.0789x; 1.0789x over previous
//
#include <hip/hip_runtime.h>
#include <math.h>

#define BB 32
#define HH 1024
#define TT 100
#define TH (TT * HH)
#define NSTEP 200
#define TILE 32768           // halves per packed [chunk 128][row 32][8] activation tile
#define SENT 0x7F7Fu         // fp16 NaN pattern used as "not yet written" sentinel

typedef _Float16 half8 __attribute__((ext_vector_type(8)));
typedef float f32x4 __attribute__((ext_vector_type(4)));
typedef unsigned int uint4v __attribute__((ext_vector_type(4)));

#define MFMA16 __builtin_amdgcn_mfma_f32_16x16x32_f16

// ---------------- coherence-point (LLC) access helpers ----------------
__device__ __forceinline__ void llc_ld_nw(const _Float16* p, half8& v) {
    asm volatile("global_load_dwordx4 %0, %1, off sc0 sc1" : "=v"(v) : "v"(p) : "memory");
}
__device__ __forceinline__ bool frag_ready(half8 v) {
    uint4v u = __builtin_bit_cast(uint4v, v);
    // one marker per 8-byte atomic unit (elements 0 and 4)
    return ((u.x & 0xFFFFu) != SENT) & ((u.z & 0xFFFFu) != SENT);
}

// ---------------- bias sum ----------------
__global__ __launch_bounds__(256) void bias_sum_kernel(
    const float* bih0, const float* bhh0, const float* bih1, const float* bhh1,
    float* bsum0, float* bsum1)
{
    int i = blockIdx.x * blockDim.x + threadIdx.x;
    if (i < 4096)      bsum0[i] = bih0[i] + bhh0[i];
    else if (i < 8192) bsum1[i - 4096] = bih1[i - 4096] + bhh1[i - 4096];
}

// ------- x / targets -> fp16, packed fragment layout [t][chunk][row][8] ------
__global__ __launch_bounds__(256) void cvt_pack_x(
    const float* __restrict__ X, const float* __restrict__ Tg,
    _Float16* __restrict__ X16, _Float16* __restrict__ Tg16)
{
    int id  = blockIdx.x * 256 + threadIdx.x;   // 0 .. 819199
    int tsr = id / 409600;
    int rem = id - tsr * 409600;
    int t   = rem >> 12;          // 0..99
    int rb  = rem & 4095;
    int h8  = rb >> 5;            // chunk 0..127
    int b   = rb & 31;            // row
    const float* s = tsr ? Tg : X;
    _Float16*    d = tsr ? Tg16 : X16;
    const float* sp = s + (size_t)b * TH + (size_t)t * HH + h8 * 8;
    float4 v0 = *(const float4*)sp;
    float4 v1 = *(const float4*)(sp + 4);
    half8 h;
    h[0] = (_Float16)v0.x; h[1] = (_Float16)v0.y; h[2] = (_Float16)v0.z; h[3] = (_Float16)v0.w;
    h[4] = (_Float16)v1.x; h[5] = (_Float16)v1.y; h[6] = (_Float16)v1.z; h[7] = (_Float16)v1.w;
    *(half8*)(d + (size_t)t * TILE + ((size_t)h8 * 32 + b) * 8) = h;
}

// ---------------- weight packing (fp16, MFMA B-fragment stream order) --------
__global__ __launch_bounds__(256) void pack_w(
    const float* __restrict__ Wih0, const float* __restrict__ Whh0,
    const float* __restrict__ Wih1, const float* __restrict__ Whh1,
    _Float16* __restrict__ Wp0, _Float16* __restrict__ Wp1)
{
    int id    = blockIdx.x * 256 + threadIdx.x;   // 0 .. 2^21-1
    int lane  = id & 63;
    int nt    = (id >> 6) & 1;
    int s     = (id >> 7) & 7;
    int w     = (id >> 10) & 7;
    int hb    = (id >> 13) & 127;
    int layer = id >> 20;
    const float* Wih = layer ? Wih1 : Wih0;
    const float* Whh = layer ? Whh1 : Whh0;
    _Float16*    Wp  = layer ? Wp1 : Wp0;

    int nl   = nt * 16 + (lane & 15);
    int gate = nl >> 3;
    int col  = hb * 8 + (nl & 7);
    int n    = gate * HH + col;
    int k    = w * 256 + s * 32 + ((lane >> 4) & 3) * 8;
    const float* src = (k < 1024) ? (Wih + (size_t)n * HH + k)
                                  : (Whh + (size_t)n * HH + (k - 1024));
    float4 v0 = *(const float4*)src;
    float4 v1 = *(const float4*)(src + 4);
    half8 d;
    d[0] = (_Float16)v0.x; d[1] = (_Float16)v0.y; d[2] = (_Float16)v0.z; d[3] = (_Float16)v0.w;
    d[4] = (_Float16)v1.x; d[5] = (_Float16)v1.y; d[6] = (_Float16)v1.z; d[7] = (_Float16)v1.w;
    *(half8*)(Wp + (size_t)(id & 0xFFFFF) * 8) = d;
}

// ---------------- persistent pipelined LSTM (pure dataflow sync) -------------
struct PArgs {
    const _Float16* X16;    // [T][TILE] packed
    const _Float16* Tg16;   // [T][TILE] packed
    const _Float16* Wp0;
    const _Float16* Wp1;
    const float* bsum0;
    const float* bsum1;
    _Float16* h0r;          // [201][TILE]; slot t+1 = h[t]; slot 0 = zeros;
    _Float16* h1r;          //   unwritten slots pre-filled with SENT pattern
    float* out;             // [B][T][H]
};

__global__ __launch_bounds__(512, 2) void lstm_persist(PArgs A)
{
    __shared__ float part[2][8][32][34];  // 69.6 KB, double-buffered
    __shared__ float ldspad[3136];        // total 82.2 KB -> 1 WG/CU

    const int wg   = blockIdx.x;
    const int role = wg >> 7;
    const int hb   = wg & 127;
    const int tid  = threadIdx.x;
    const int w    = tid >> 6;
    const int lane = tid & 63;
    const int lr   = lane & 15;
    const int lg   = lane >> 4;
    const bool isx = (w < 4);

    if (A.out == (float*)1) {             // never true; keeps ldspad allocated
        ldspad[tid] = (float)tid;
        part[0][0][0][0] = ldspad[511 - tid];
    }

    const _Float16* Wp   = role ? A.Wp1 : A.Wp0;
    const float* bsum    = role ? A.bsum1 : A.bsum0;
    _Float16* ring_self  = role ? A.h1r : A.h0r;

    // ---- one-time: weight slice -> registers ----
    half8 wreg[16];
    {
        const half8* wp = (const half8*)Wp + (size_t)(hb * 8 + w) * 1024 + lane;
#pragma unroll
        for (int sn = 0; sn < 16; ++sn) wreg[sn] = wp[(size_t)sn * 64];
    }

    const int eb = tid >> 3, ec = tid & 7, ecol = hb * 8 + ec;
    float breg[4], creg = 0.f;
    if (tid < 256) {
#pragma unroll
        for (int g = 0; g < 4; ++g) breg[g] = bsum[g * HH + ecol];
    }

    // per-lane A-fragment offset within a packed tile (halves)
    const size_t afrag = (size_t)((w & 3) * 32 + lg) * 256 + (size_t)lr * 8;
    bool dead = false;

    for (int p = 0; p < NSTEP; ++p) {
        half8 a[16];
        const bool early = isx && role == 0 && p != 100;
        if (early) {
            // static input: plain cached loads
            const _Float16* aptr = ((p < 100) ? A.X16 + (size_t)p * TILE
                                              : A.Tg16 + (size_t)(p - 100) * TILE) + afrag;
#pragma unroll
            for (int s = 0; s < 8; ++s) {
                a[2 * s]     = *(const half8*)(aptr + s * 1024);
                a[2 * s + 1] = *(const half8*)(aptr + s * 1024 + 128);
            }
        } else {
            // ring tile: fused poll+fetch — every spin iteration issues all 16
            // sc fragments; on the exit iteration the data is already in regs.
            // (r11 structure; h-waves enter here IMMEDIATELY after their
            // partials write — no end-of-step barrier — so the spin is in
            // steady cadence when the producers' stores land.)
            const _Float16* abase;
            if (isx) abase = role ? A.h0r + (size_t)(p + 1) * TILE
                                  : A.h1r + (size_t)100 * TILE;   // p==100
            else     abase = ring_self + (size_t)p * TILE;
            const _Float16* aptr = abase + afrag;

            unsigned spins = 0;
            for (;;) {
                llc_ld_nw(aptr,       a[0]);
                llc_ld_nw(aptr + 128, a[1]);
#pragma unroll
                for (int s = 1; s < 8; ++s) {
                    llc_ld_nw(aptr + s * 1024,       a[2 * s]);
                    llc_ld_nw(aptr + s * 1024 + 128, a[2 * s + 1]);
                }
                asm volatile("s_waitcnt vmcnt(0)"
                    : "+v"(a[0]),  "+v"(a[1]),  "+v"(a[2]),  "+v"(a[3]),
                      "+v"(a[4]),  "+v"(a[5]),  "+v"(a[6]),  "+v"(a[7]),
                      "+v"(a[8]),  "+v"(a[9]),  "+v"(a[10]), "+v"(a[11]),
                      "+v"(a[12]), "+v"(a[13]), "+v"(a[14]), "+v"(a[15])
                    :: "memory");
                __builtin_amdgcn_sched_barrier(0);
                bool ok = true;
#pragma unroll
                for (int i = 0; i < 16; ++i) ok &= frag_ready(a[i]);
                if (__all(ok) || dead) break;
                __builtin_amdgcn_s_sleep(1);
                if (++spins > (1u << 20)) dead = true;
            }
        }

        // ---------- MFMA: 32 per wave, weights from registers ----------
        f32x4 acc[2][2] = {};
#pragma unroll
        for (int s = 0; s < 8; ++s) {
            acc[0][0] = MFMA16(a[2 * s],     wreg[2 * s],     acc[0][0], 0, 0, 0);
            acc[0][1] = MFMA16(a[2 * s],     wreg[2 * s + 1], acc[0][1], 0, 0, 0);
            acc[1][0] = MFMA16(a[2 * s + 1], wreg[2 * s],     acc[1][0], 0, 0, 0);
            acc[1][1] = MFMA16(a[2 * s + 1], wreg[2 * s + 1], acc[1][1], 0, 0, 0);
        }

        // ---------- cross-wave reduction (double-buffered) ----------
        float (*pb)[32][34] = part[p & 1];
#pragma unroll
        for (int mt = 0; mt < 2; ++mt)
#pragma unroll
            for (int nt = 0; nt < 2; ++nt)
#pragma unroll
                for (int j = 0; j < 4; ++j)
                    pb[w][16 * mt + lg * 4 + j][16 * nt + lr] = acc[mt][nt][j];
        __syncthreads();   // partials of step p complete

        // ---------- fused cell epilogue (waves 0-3 only) ----------
        if (tid < 256) {
            float g4[4];
#pragma unroll
            for (int g = 0; g < 4; ++g) {
                float s0 = 0.f;
#pragma unroll
                for (int pw = 0; pw < 8; ++pw) s0 += pb[pw][eb][g * 8 + ec];
                g4[g] = s0 + breg[g];
            }
            float ig = 1.f / (1.f + __expf(-g4[0]));
            float fg = 1.f / (1.f + __expf(-g4[1]));
            float gg = 2.f / (1.f + __expf(-2.f * g4[2])) - 1.f;
            float og = 1.f / (1.f + __expf(-g4[3]));
            float cn = fg * creg + ig * gg;
            float tc = 2.f / (1.f + __expf(-2.f * cn)) - 1.f;
            float hn = og * tc;
            creg = cn;

            // pack 4 adjacent u16 h values -> one 8B agent-scope atomic swap
            unsigned hv = (unsigned)__builtin_bit_cast(unsigned short, (_Float16)hn);
            unsigned o1  = __shfl_xor(hv, 1, 64);
            unsigned w32 = hv | (o1 << 16);                 // valid on even tid
            unsigned o2  = __shfl_xor(w32, 2, 64);
            if ((tid & 3) == 0) {
                unsigned long long d64 =
                    ((unsigned long long)o2 << 32) | (unsigned long long)w32;
                unsigned long long* dst = (unsigned long long*)
                    (ring_self + (size_t)(p + 1) * TILE + hb * 256 + tid);
                __hip_atomic_exchange(dst, d64, __ATOMIC_RELAXED,
                                      __HIP_MEMORY_SCOPE_AGENT);
            }
            if (role && p >= 100)
                A.out[(size_t)eb * TH + (size_t)(p - 100) * HH + ecol] = hn;
        }
        // NO end-of-step barrier: part[] is double-buffered. WAR safety by
        // induction — h-waves' step-(p+2) writes to part[p&1] sit behind
        // barrier1(p+1), which waves 0-3 reach only after this epilogue has
        // finished reading part[p&1]. h-waves proceed straight to the next
        // spin, hiding the epilogue+store latency under detect.
    }
}

extern "C" void kernel_launch(void* const* d_in, const int* in_sizes, int n_in,
                              void* d_out, int out_size, void* d_ws, size_t ws_size,
                              hipStream_t stream)
{
    const float* X    = (const float*)d_in[0];
    const float* Tg   = (const float*)d_in[1];
    const float* Wih0 = (const float*)d_in[2];
    const float* Whh0 = (const float*)d_in[3];
    const float* bih0 = (const float*)d_in[4];
    const float* bhh0 = (const float*)d_in[5];
    const float* Wih1 = (const float*)d_in[6];
    const float* Whh1 = (const float*)d_in[7];
    const float* bih1 = (const float*)d_in[8];
    const float* bhh1 = (const float*)d_in[9];
    float* out = (float*)d_out;

    const size_t ringBytes = (size_t)201 * TILE * 2;   // 13.2 MB
    char* p = (char*)d_ws;
    _Float16* h0r = (_Float16*)p; p += ringBytes;
    _Float16* h1r = (_Float16*)p; p += ringBytes;
    float* bsum0 = (float*)p; p += 4096 * sizeof(float);
    float* bsum1 = (float*)p; p += 4096 * sizeof(float);
    _Float16* X16  = (_Float16*)p; p += (size_t)TT * TILE * 2;
    _Float16* Tg16 = (_Float16*)p; p += (size_t)TT * TILE * 2;
    _Float16* Wp0  = (_Float16*)p; p += (size_t)4096 * 2048 * 2;
    _Float16* Wp1  = (_Float16*)p;

    // sentinel-fill rings (0x7F7F halves = fp16 NaN, unreachable by tanh*sig),
    // then zero slot 0 of each ring (h[-1] = 0)
    hipMemsetAsync(h0r, 0x7F, ringBytes, stream);
    hipMemsetAsync(h1r, 0x7F, ringBytes, stream);
    hipMemsetAsync(h0r, 0, (size_t)TILE * 2, stream);
    hipMemsetAsync(h1r, 0, (size_t)TILE * 2, stream);

    bias_sum_kernel<<<32, 256, 0, stream>>>(bih0, bhh0, bih1, bhh1, bsum0, bsum1);
    cvt_pack_x<<<3200, 256, 0, stream>>>(X, Tg, X16, Tg16);
    pack_w<<<8192, 256, 0, stream>>>(Wih0, Whh0, Wih1, Whh1, Wp0, Wp1);

    PArgs A;
    A.X16 = X16; A.Tg16 = Tg16; A.Wp0 = Wp0; A.Wp1 = Wp1;
    A.bsum0 = bsum0; A.bsum1 = bsum1;
    A.h0r = h0r; A.h1r = h1r;
    A.out = out;
    lstm_persist<<<256, 512, 0, stream>>>(A);
}

// Round 17
// 597.284 us; speedup vs baseline: 1.5782x; 1.4628x over previous
//
#include <hip/hip_runtime.h>
#include <math.h>

#define BB 32
#define HH 1024
#define TT 100
#define TH (TT * HH)
#define NSTEP 200
#define TILE 32768           // halves per packed [chunk 128][row 32][8] activation tile
#define SENT 0x7F7Fu         // fp16 NaN pattern used as "not yet written" sentinel

typedef _Float16 half8 __attribute__((ext_vector_type(8)));
typedef float f32x4 __attribute__((ext_vector_type(4)));
typedef unsigned int uint4v __attribute__((ext_vector_type(4)));

#define MFMA16 __builtin_amdgcn_mfma_f32_16x16x32_f16

// ---------------- coherence-point (LLC) access helpers ----------------
__device__ __forceinline__ void llc_ld_nw(const _Float16* p, half8& v) {
    asm volatile("global_load_dwordx4 %0, %1, off sc0 sc1" : "=v"(v) : "v"(p) : "memory");
}
__device__ __forceinline__ bool frag_ready(half8 v) {
    uint4v u = __builtin_bit_cast(uint4v, v);
    // one marker per 8-byte atomic unit (elements 0 and 4)
    return ((u.x & 0xFFFFu) != SENT) & ((u.z & 0xFFFFu) != SENT);
}

// ---------------- bias sum ----------------
__global__ __launch_bounds__(256) void bias_sum_kernel(
    const float* bih0, const float* bhh0, const float* bih1, const float* bhh1,
    float* bsum0, float* bsum1)
{
    int i = blockIdx.x * blockDim.x + threadIdx.x;
    if (i < 4096)      bsum0[i] = bih0[i] + bhh0[i];
    else if (i < 8192) bsum1[i - 4096] = bih1[i - 4096] + bhh1[i - 4096];
}

// ------- x / targets -> fp16, packed fragment layout [t][chunk][row][8] ------
__global__ __launch_bounds__(256) void cvt_pack_x(
    const float* __restrict__ X, const float* __restrict__ Tg,
    _Float16* __restrict__ X16, _Float16* __restrict__ Tg16)
{
    int id  = blockIdx.x * 256 + threadIdx.x;   // 0 .. 819199
    int tsr = id / 409600;
    int rem = id - tsr * 409600;
    int t   = rem >> 12;          // 0..99
    int rb  = rem & 4095;
    int h8  = rb >> 5;            // chunk 0..127
    int b   = rb & 31;            // row
    const float* s = tsr ? Tg : X;
    _Float16*    d = tsr ? Tg16 : X16;
    const float* sp = s + (size_t)b * TH + (size_t)t * HH + h8 * 8;
    float4 v0 = *(const float4*)sp;
    float4 v1 = *(const float4*)(sp + 4);
    half8 h;
    h[0] = (_Float16)v0.x; h[1] = (_Float16)v0.y; h[2] = (_Float16)v0.z; h[3] = (_Float16)v0.w;
    h[4] = (_Float16)v1.x; h[5] = (_Float16)v1.y; h[6] = (_Float16)v1.z; h[7] = (_Float16)v1.w;
    *(half8*)(d + (size_t)t * TILE + ((size_t)h8 * 32 + b) * 8) = h;
}

// ---------------- weight packing (fp16, MFMA B-fragment stream order) --------
__global__ __launch_bounds__(256) void pack_w(
    const float* __restrict__ Wih0, const float* __restrict__ Whh0,
    const float* __restrict__ Wih1, const float* __restrict__ Whh1,
    _Float16* __restrict__ Wp0, _Float16* __restrict__ Wp1)
{
    int id    = blockIdx.x * 256 + threadIdx.x;   // 0 .. 2^21-1
    int lane  = id & 63;
    int nt    = (id >> 6) & 1;
    int s     = (id >> 7) & 7;
    int w     = (id >> 10) & 7;
    int hb    = (id >> 13) & 127;
    int layer = id >> 20;
    const float* Wih = layer ? Wih1 : Wih0;
    const float* Whh = layer ? Whh1 : Whh0;
    _Float16*    Wp  = layer ? Wp1 : Wp0;

    int nl   = nt * 16 + (lane & 15);
    int gate = nl >> 3;
    int col  = hb * 8 + (nl & 7);
    int n    = gate * HH + col;
    int k    = w * 256 + s * 32 + ((lane >> 4) & 3) * 8;
    const float* src = (k < 1024) ? (Wih + (size_t)n * HH + k)
                                  : (Whh + (size_t)n * HH + (k - 1024));
    float4 v0 = *(const float4*)src;
    float4 v1 = *(const float4*)(src + 4);
    half8 d;
    d[0] = (_Float16)v0.x; d[1] = (_Float16)v0.y; d[2] = (_Float16)v0.z; d[3] = (_Float16)v0.w;
    d[4] = (_Float16)v1.x; d[5] = (_Float16)v1.y; d[6] = (_Float16)v1.z; d[7] = (_Float16)v1.w;
    *(half8*)(Wp + (size_t)(id & 0xFFFFF) * 8) = d;
}

// ---------------- persistent pipelined LSTM (pure dataflow sync) -------------
struct PArgs {
    const _Float16* X16;    // [T][TILE] packed
    const _Float16* Tg16;   // [T][TILE] packed
    const _Float16* Wp0;
    const _Float16* Wp1;
    const float* bsum0;
    const float* bsum1;
    _Float16* h0r;          // [201][TILE]; slot t+1 = h[t]; slot 0 = zeros;
    _Float16* h1r;          //   unwritten slots pre-filled with SENT pattern
    float* out;             // [B][T][H]
};

__global__ __launch_bounds__(512, 2) void lstm_persist(PArgs A)
{
    __shared__ float part[8][32][34];     // 34.8 KB
    __shared__ float ldspad[11776];       // total 80 KB -> 1 WG/CU

    const int wg   = blockIdx.x;
    const int role = wg >> 7;
    const int hb   = wg & 127;
    const int tid  = threadIdx.x;
    const int w    = tid >> 6;
    const int lane = tid & 63;
    const int lr   = lane & 15;
    const int lg   = lane >> 4;
    const bool isx = (w < 4);

    if (A.out == (float*)1) {             // never true; keeps ldspad allocated
        ldspad[tid] = (float)tid;
        part[0][0][0] = ldspad[511 - tid];
    }

    const _Float16* Wp   = role ? A.Wp1 : A.Wp0;
    const float* bsum    = role ? A.bsum1 : A.bsum0;
    _Float16* ring_self  = role ? A.h1r : A.h0r;

    // ---- one-time: weight slice -> registers ----
    half8 wreg[16];
    {
        const half8* wp = (const half8*)Wp + (size_t)(hb * 8 + w) * 1024 + lane;
#pragma unroll
        for (int sn = 0; sn < 16; ++sn) wreg[sn] = wp[(size_t)sn * 64];
    }

    const int eb = tid >> 3, ec = tid & 7, ecol = hb * 8 + ec;
    float breg[4], creg = 0.f;
    if (tid < 256) {
#pragma unroll
        for (int g = 0; g < 4; ++g) breg[g] = bsum[g * HH + ecol];
    }

    // per-lane A-fragment offset within a packed tile (halves)
    const size_t afrag = (size_t)((w & 3) * 32 + lg) * 256 + (size_t)lr * 8;
    bool dead = false;

    for (int p = 0; p < NSTEP; ++p) {
        half8 a[16];
        const bool early = isx && role == 0 && p != 100;
        if (early) {
            // static input: plain cached loads
            const _Float16* aptr = ((p < 100) ? A.X16 + (size_t)p * TILE
                                              : A.Tg16 + (size_t)(p - 100) * TILE) + afrag;
#pragma unroll
            for (int s = 0; s < 8; ++s) {
                a[2 * s]     = *(const half8*)(aptr + s * 1024);
                a[2 * s + 1] = *(const half8*)(aptr + s * 1024 + 128);
            }
        } else {
            // ring tile: FUSED poll+fetch — every spin iteration issues all 16
            // sc fragments; on the exit iteration the data is already in regs,
            // so detection and data movement share one LLC round trip.
            const _Float16* abase;
            if (isx) abase = role ? A.h0r + (size_t)(p + 1) * TILE
                                  : A.h1r + (size_t)100 * TILE;   // p==100
            else     abase = ring_self + (size_t)p * TILE;
            const _Float16* aptr = abase + afrag;

            unsigned spins = 0;
            for (;;) {
                llc_ld_nw(aptr,       a[0]);
                llc_ld_nw(aptr + 128, a[1]);
#pragma unroll
                for (int s = 1; s < 8; ++s) {
                    llc_ld_nw(aptr + s * 1024,       a[2 * s]);
                    llc_ld_nw(aptr + s * 1024 + 128, a[2 * s + 1]);
                }
                asm volatile("s_waitcnt vmcnt(0)"
                    : "+v"(a[0]),  "+v"(a[1]),  "+v"(a[2]),  "+v"(a[3]),
                      "+v"(a[4]),  "+v"(a[5]),  "+v"(a[6]),  "+v"(a[7]),
                      "+v"(a[8]),  "+v"(a[9]),  "+v"(a[10]), "+v"(a[11]),
                      "+v"(a[12]), "+v"(a[13]), "+v"(a[14]), "+v"(a[15])
                    :: "memory");
                __builtin_amdgcn_sched_barrier(0);
                bool ok = true;
#pragma unroll
                for (int i = 0; i < 16; ++i) ok &= frag_ready(a[i]);
                if (__all(ok) || dead) break;
                __builtin_amdgcn_s_sleep(1);
                if (++spins > (1u << 20)) dead = true;
            }
        }

        // ---------- MFMA: 32 per wave, weights from registers ----------
        f32x4 acc[2][2] = {};
#pragma unroll
        for (int s = 0; s < 8; ++s) {
            acc[0][0] = MFMA16(a[2 * s],     wreg[2 * s],     acc[0][0], 0, 0, 0);
            acc[0][1] = MFMA16(a[2 * s],     wreg[2 * s + 1], acc[0][1], 0, 0, 0);
            acc[1][0] = MFMA16(a[2 * s + 1], wreg[2 * s],     acc[1][0], 0, 0, 0);
            acc[1][1] = MFMA16(a[2 * s + 1], wreg[2 * s + 1], acc[1][1], 0, 0, 0);
        }

        // ---------- cross-wave reduction ----------
#pragma unroll
        for (int mt = 0; mt < 2; ++mt)
#pragma unroll
            for (int nt = 0; nt < 2; ++nt)
#pragma unroll
                for (int j = 0; j < 4; ++j)
                    part[w][16 * mt + lg * 4 + j][16 * nt + lr] = acc[mt][nt][j];
        __syncthreads();

        // ---------- fused cell epilogue ----------
        if (tid < 256) {
            float g4[4];
#pragma unroll
            for (int g = 0; g < 4; ++g) {
                float s0 = 0.f;
#pragma unroll
                for (int pw = 0; pw < 8; ++pw) s0 += part[pw][eb][g * 8 + ec];
                g4[g] = s0 + breg[g];
            }
            float ig = 1.f / (1.f + __expf(-g4[0]));
            float fg = 1.f / (1.f + __expf(-g4[1]));
            float gg = 2.f / (1.f + __expf(-2.f * g4[2])) - 1.f;
            float og = 1.f / (1.f + __expf(-g4[3]));
            float cn = fg * creg + ig * gg;
            float tc = 2.f / (1.f + __expf(-2.f * cn)) - 1.f;
            float hn = og * tc;
            creg = cn;

            // pack 4 adjacent u16 h values -> one 8B agent-scope atomic swap
            unsigned hv = (unsigned)__builtin_bit_cast(unsigned short, (_Float16)hn);
            unsigned o1  = __shfl_xor(hv, 1, 64);
            unsigned w32 = hv | (o1 << 16);                 // valid on even tid
            unsigned o2  = __shfl_xor(w32, 2, 64);
            if ((tid & 3) == 0) {
                unsigned long long d64 =
                    ((unsigned long long)o2 << 32) | (unsigned long long)w32;
                unsigned long long* dst = (unsigned long long*)
                    (ring_self + (size_t)(p + 1) * TILE + hb * 256 + tid);
                __hip_atomic_exchange(dst, d64, __ATOMIC_RELAXED,
                                      __HIP_MEMORY_SCOPE_AGENT);
            }
            if (role && p >= 100)
                A.out[(size_t)eb * TH + (size_t)(p - 100) * HH + ecol] = hn;
        }
        __syncthreads();   // protects part[] across steps; atomics already issued
    }
}

extern "C" void kernel_launch(void* const* d_in, const int* in_sizes, int n_in,
                              void* d_out, int out_size, void* d_ws, size_t ws_size,
                              hipStream_t stream)
{
    const float* X    = (const float*)d_in[0];
    const float* Tg   = (const float*)d_in[1];
    const float* Wih0 = (const float*)d_in[2];
    const float* Whh0 = (const float*)d_in[3];
    const float* bih0 = (const float*)d_in[4];
    const float* bhh0 = (const float*)d_in[5];
    const float* Wih1 = (const float*)d_in[6];
    const float* Whh1 = (const float*)d_in[7];
    const float* bih1 = (const float*)d_in[8];
    const float* bhh1 = (const float*)d_in[9];
    float* out = (float*)d_out;

    const size_t ringBytes = (size_t)201 * TILE * 2;   // 13.2 MB
    char* p = (char*)d_ws;
    _Float16* h0r = (_Float16*)p; p += ringBytes;
    _Float16* h1r = (_Float16*)p; p += ringBytes;
    float* bsum0 = (float*)p; p += 4096 * sizeof(float);
    float* bsum1 = (float*)p; p += 4096 * sizeof(float);
    _Float16* X16  = (_Float16*)p; p += (size_t)TT * TILE * 2;
    _Float16* Tg16 = (_Float16*)p; p += (size_t)TT * TILE * 2;
    _Float16* Wp0  = (_Float16*)p; p += (size_t)4096 * 2048 * 2;
    _Float16* Wp1  = (_Float16*)p;

    // sentinel-fill rings (0x7F7F halves = fp16 NaN, unreachable by tanh*sig),
    // then zero slot 0 of each ring (h[-1] = 0)
    hipMemsetAsync(h0r, 0x7F, ringBytes, stream);
    hipMemsetAsync(h1r, 0x7F, ringBytes, stream);
    hipMemsetAsync(h0r, 0, (size_t)TILE * 2, stream);
    hipMemsetAsync(h1r, 0, (size_t)TILE * 2, stream);

    bias_sum_kernel<<<32, 256, 0, stream>>>(bih0, bhh0, bih1, bhh1, bsum0, bsum1);
    cvt_pack_x<<<3200, 256, 0, stream>>>(X, Tg, X16, Tg16);
    pack_w<<<8192, 256, 0, stream>>>(Wih0, Whh0, Wih1, Whh1, Wp0, Wp1);

    PArgs A;
    A.X16 = X16; A.Tg16 = Tg16; A.Wp0 = Wp0; A.Wp1 = Wp1;
    A.bsum0 = bsum0; A.bsum1 = bsum1;
    A.h0r = h0r; A.h1r = h1r;
    A.out = out;
    lstm_persist<<<256, 512, 0, stream>>>(A);
}